// Round 1
// baseline (23.832 us; speedup 1.0000x reference)
//
#include <hip/hip_runtime.h>

// GNFConverter: per (b,p) point, per-type softmax over atoms of dist-logits,
// weighted sum of (coord - query) diffs, clipped to magnitude 0.3.
// Shapes fixed by setup_inputs(): B=8, A=128, P=8192, T=5.

#define B_DIM 8
#define A_DIM 128
#define P_DIM 8192
#define N_TYPES 5

__global__ __launch_bounds__(256) void gnf_kernel(
    const float* __restrict__ coords,     // (B, A, 3) f32
    const int*   __restrict__ atom_types, // (B, A) i32
    const float* __restrict__ query,      // (B, P, 3) f32
    float*       __restrict__ out)        // (B, P, T, 3) f32
{
    __shared__ float4 s_atoms[A_DIM];  // x, y, z, type (bitcast int)

    const int blocks_per_b = P_DIM / 256;          // 32
    const int b  = blockIdx.x / blocks_per_b;
    const int p0 = (blockIdx.x % blocks_per_b) * 256;
    const int tid = threadIdx.x;

    // Stage this batch's atoms into LDS (one float4 per atom).
    if (tid < A_DIM) {
        const float* c = coords + (size_t)(b * A_DIM + tid) * 3;
        int t = atom_types[b * A_DIM + tid];
        s_atoms[tid] = make_float4(c[0], c[1], c[2], __int_as_float(t));
    }
    __syncthreads();

    const int p = p0 + tid;
    const float* q = query + (size_t)(b * P_DIM + p) * 3;
    const float qx = q[0], qy = q[1], qz = q[2];

    // Per-type accumulators: denom + 3-vector numerator. All indices
    // compile-time (unrolled) so these stay in VGPRs.
    float s [N_TYPES];
    float gx[N_TYPES], gy[N_TYPES], gz[N_TYPES];
#pragma unroll
    for (int t = 0; t < N_TYPES; ++t) { s[t] = 0.f; gx[t] = 0.f; gy[t] = 0.f; gz[t] = 0.f; }

    // Single pass: exp(-dist) needs no max-subtraction (logit <= 0, no
    // overflow; dist is O(10) max for N(0,1) data, no underflow).
#pragma unroll 4
    for (int a = 0; a < A_DIM; ++a) {
        const float4 at = s_atoms[a];            // wave-uniform -> LDS broadcast
        const float dx = at.x - qx;
        const float dy = at.y - qy;
        const float dz = at.z - qz;
        const float d2 = fmaf(dx, dx, fmaf(dy, dy, dz * dz));
        const float dist = sqrtf(d2);
        const float e = __builtin_exp2f(dist * -1.44269504088896340736f); // exp(-dist)
        const int ty = __float_as_int(at.w);
#pragma unroll
        for (int t = 0; t < N_TYPES; ++t) {
            const float val = (ty == t) ? e : 0.0f;  // handles padding (-1) too
            s[t] += val;
            gx[t] = fmaf(val, dx, gx[t]);
            gy[t] = fmaf(val, dy, gy[t]);
            gz[t] = fmaf(val, dz, gz[t]);
        }
    }

    // Normalize per type, clip magnitude to 0.3, store 15 f32.
    float* o = out + (size_t)(b * P_DIM + p) * (N_TYPES * 3);
#pragma unroll
    for (int t = 0; t < N_TYPES; ++t) {
        const float inv = (s[t] > 0.f) ? (1.0f / s[t]) : 0.0f;
        float x = gx[t] * inv;
        float y = gy[t] * inv;
        float z = gz[t] * inv;
        const float mag2 = fmaf(x, x, fmaf(y, y, z * z));
        const float mag = sqrtf(mag2);
        if (mag > 0.3f) {
            const float sc = 0.3f / mag;
            x *= sc; y *= sc; z *= sc;
        }
        o[t * 3 + 0] = x;
        o[t * 3 + 1] = y;
        o[t * 3 + 2] = z;
    }
}

extern "C" void kernel_launch(void* const* d_in, const int* in_sizes, int n_in,
                              void* d_out, int out_size, void* d_ws, size_t ws_size,
                              hipStream_t stream) {
    const float* coords     = (const float*)d_in[0];
    const int*   atom_types = (const int*)d_in[1];
    const float* query      = (const float*)d_in[2];
    float*       out        = (float*)d_out;

    const int nblocks = (B_DIM * P_DIM) / 256;  // 256
    gnf_kernel<<<nblocks, 256, 0, stream>>>(coords, atom_types, query, out);
}

// Round 2
// 17.359 us; speedup vs baseline: 1.3729x; 1.3729x over previous
//
#include <hip/hip_runtime.h>

// GNFConverter: per (b,p) point, per-type softmax over atoms of -dist logits,
// weighted sum of (coord - query) diffs, clipped to magnitude 0.3.
// Shapes fixed: B=8, A=128, P=8192, T=5.
//
// Strategy: count-sort atoms by type into LDS segments (once per block), then
// each point's atom loop runs type-by-type with only 4 accumulators and no
// per-type predication. Each point is split across KSPLIT=4 threads for
// 4 waves/SIMD occupancy; partial sums reduced via __shfl_xor butterfly.

#define B_DIM 8
#define A_DIM 128
#define P_DIM 8192
#define N_TYPES 5
#define KSPLIT 4
#define PTS_PER_BLOCK 64   // 256 threads / KSPLIT

__global__ __launch_bounds__(256) void gnf_kernel(
    const float* __restrict__ coords,     // (B, A, 3) f32
    const int*   __restrict__ atom_types, // (B, A) i32
    const float* __restrict__ query,      // (B, P, 3) f32
    float*       __restrict__ out)        // (B, P, T, 3) f32
{
    __shared__ float4 s_atoms[A_DIM];        // type-sorted (x,y,z,unused)
    __shared__ int s_cnt[N_TYPES];
    __shared__ int s_seg[N_TYPES + 1];       // segment starts (prefix sums)
    __shared__ int s_cur[N_TYPES];           // scatter cursors

    const int blocks_per_b = P_DIM / PTS_PER_BLOCK;   // 128
    const int b  = blockIdx.x / blocks_per_b;
    const int p0 = (blockIdx.x % blocks_per_b) * PTS_PER_BLOCK;
    const int tid = threadIdx.x;

    // ---- count-sort atoms by type into LDS segments ----
    if (tid < N_TYPES) s_cnt[tid] = 0;
    __syncthreads();

    float ax = 0.f, ay = 0.f, az = 0.f;
    int ty = -1;
    if (tid < A_DIM) {
        const float* c = coords + (size_t)(b * A_DIM + tid) * 3;
        ax = c[0]; ay = c[1]; az = c[2];
        int t = atom_types[b * A_DIM + tid];
        if (t >= 0 && t < N_TYPES) {
            ty = t;
            atomicAdd(&s_cnt[t], 1);
        }
    }
    __syncthreads();
    if (tid == 0) {
        int run = 0;
#pragma unroll
        for (int t = 0; t < N_TYPES; ++t) {
            s_seg[t] = run; s_cur[t] = run; run += s_cnt[t];
        }
        s_seg[N_TYPES] = run;
    }
    __syncthreads();
    if (ty >= 0) {
        int pos = atomicAdd(&s_cur[ty], 1);
        s_atoms[pos] = make_float4(ax, ay, az, 0.f);
    }
    __syncthreads();

    // segment bounds -> registers (compile-time indexed)
    int seg[N_TYPES + 1];
#pragma unroll
    for (int t = 0; t <= N_TYPES; ++t) seg[t] = s_seg[t];

    // ---- main: each point handled by 4 adjacent lanes (k = tid&3) ----
    const int k = tid & (KSPLIT - 1);
    const int p = p0 + (tid >> 2);
    const float* q = query + (size_t)(b * P_DIM + p) * 3;
    const float qx = q[0], qy = q[1], qz = q[2];
    float* o = out + (size_t)(b * P_DIM + p) * (N_TYPES * 3);

#pragma unroll
    for (int t = 0; t < N_TYPES; ++t) {
        float s = 0.f, gx = 0.f, gy = 0.f, gz = 0.f;
        for (int i = seg[t] + k; i < seg[t + 1]; i += KSPLIT) {
            const float4 at = s_atoms[i];
            const float dx = at.x - qx;
            const float dy = at.y - qy;
            const float dz = at.z - qz;
            const float d2 = fmaf(dx, dx, fmaf(dy, dy, dz * dz));
            const float dist = sqrtf(d2);
            const float e = __builtin_exp2f(dist * -1.44269504088896340736f);
            s += e;
            gx = fmaf(e, dx, gx);
            gy = fmaf(e, dy, gy);
            gz = fmaf(e, dz, gz);
        }
        // butterfly reduce across the 4 k-lanes (all lanes get the total)
        s  += __shfl_xor(s, 1);  s  += __shfl_xor(s, 2);
        gx += __shfl_xor(gx, 1); gx += __shfl_xor(gx, 2);
        gy += __shfl_xor(gy, 1); gy += __shfl_xor(gy, 2);
        gz += __shfl_xor(gz, 1); gz += __shfl_xor(gz, 2);

        const float inv = (s > 0.f) ? (1.0f / s) : 0.0f;
        float x = gx * inv, y = gy * inv, z = gz * inv;
        const float mag = sqrtf(fmaf(x, x, fmaf(y, y, z * z)));
        if (mag > 0.3f) {
            const float sc = 0.3f / mag;
            x *= sc; y *= sc; z *= sc;
        }
        // lanes k=0,1,2 store components x,y,z
        const float val = (k == 0) ? x : ((k == 1) ? y : z);
        if (k < 3) o[t * 3 + k] = val;
    }
}

extern "C" void kernel_launch(void* const* d_in, const int* in_sizes, int n_in,
                              void* d_out, int out_size, void* d_ws, size_t ws_size,
                              hipStream_t stream) {
    const float* coords     = (const float*)d_in[0];
    const int*   atom_types = (const int*)d_in[1];
    const float* query      = (const float*)d_in[2];
    float*       out        = (float*)d_out;

    const int nblocks = (B_DIM * P_DIM * KSPLIT) / 256;  // 1024
    gnf_kernel<<<nblocks, 256, 0, stream>>>(coords, atom_types, query, out);
}